// Round 1
// baseline (291.668 us; speedup 1.0000x reference)
//
#include <hip/hip_runtime.h>
#include <stdint.h>

#define B_  4
#define S_  1024
#define D_  1024
#define H_  16
#define HD_ 64
#define E_  2048   // 2*D
#define C2_ 128    // 2*HD

typedef __attribute__((ext_vector_type(8))) short          bf16x8;  // MFMA A/B frag (8 bf16)
typedef __attribute__((ext_vector_type(8))) unsigned short u16x8;
typedef __attribute__((ext_vector_type(4))) unsigned short u16x4;
typedef __attribute__((ext_vector_type(4))) float          f32x4;   // MFMA C/D frag

__device__ __forceinline__ unsigned short f2bf(float f) {
  union { float f; unsigned int u; } v; v.f = f;
  unsigned int r = v.u + 0x7fffu + ((v.u >> 16) & 1u);   // RNE
  return (unsigned short)(r >> 16);
}

// ---------------- LayerNorm (D=1024) + bf16 cast ----------------
__global__ __launch_bounds__(256) void ln_cast_k(const float* __restrict__ x,
                                                 const float* __restrict__ g,
                                                 const float* __restrict__ bb,
                                                 unsigned short* __restrict__ out) {
  int row = blockIdx.x;
  int tid = threadIdx.x;
  const float* xr = x + (size_t)row * D_;
  float4 xv = *(const float4*)(xr + tid * 4);
  float s  = xv.x + xv.y + xv.z + xv.w;
  float sq = xv.x * xv.x + xv.y * xv.y + xv.z * xv.z + xv.w * xv.w;
#pragma unroll
  for (int m = 32; m; m >>= 1) { s += __shfl_xor(s, m, 64); sq += __shfl_xor(sq, m, 64); }
  __shared__ float ps[4], pq[4];
  int w = tid >> 6, l = tid & 63;
  if (l == 0) { ps[w] = s; pq[w] = sq; }
  __syncthreads();
  s  = ps[0] + ps[1] + ps[2] + ps[3];
  sq = pq[0] + pq[1] + pq[2] + pq[3];
  float mean = s * (1.f / D_);
  float var  = sq * (1.f / D_) - mean * mean;
  float rstd = rsqrtf(var + 1e-5f);
  float4 gv = *(const float4*)(g + tid * 4);
  float4 bv = *(const float4*)(bb + tid * 4);
  u16x4 o;
  o.x = f2bf((xv.x - mean) * rstd * gv.x + bv.x);
  o.y = f2bf((xv.y - mean) * rstd * gv.y + bv.y);
  o.z = f2bf((xv.z - mean) * rstd * gv.z + bv.z);
  o.w = f2bf((xv.w - mean) * rstd * gv.w + bv.w);
  *(u16x4*)(out + (size_t)row * D_ + tid * 4) = o;
}

// ---------------- fp32 -> bf16 cast (weights) ----------------
__global__ __launch_bounds__(256) void cast_k(const float* __restrict__ in,
                                              unsigned short* __restrict__ out, int n4) {
  int i = blockIdx.x * 256 + threadIdx.x;
  if (i < n4) {
    float4 v = *(const float4*)(in + (size_t)i * 4);
    u16x4 o; o.x = f2bf(v.x); o.y = f2bf(v.y); o.z = f2bf(v.z); o.w = f2bf(v.w);
    *(u16x4*)(out + (size_t)i * 4) = o;
  }
}

// ---------------- projection GEMM: C = A(M,K) @ W(N,K)^T, bf16, 128x128 tile ----------------
// z selects (A, W, O); output scattered into (b,h,s,c) head layout.
__global__ __launch_bounds__(256) void gemm_proj_k(
    const unsigned short* __restrict__ qln, const unsigned short* __restrict__ kvln,
    const unsigned short* __restrict__ Wq,  const unsigned short* __restrict__ Wk,
    const unsigned short* __restrict__ Wv,
    unsigned short* __restrict__ qb, unsigned short* __restrict__ kb,
    unsigned short* __restrict__ vb) {
  const int K = D_;
  int which = blockIdx.z;
  const unsigned short* A = (which == 0) ? qln : kvln;
  const unsigned short* W = (which == 0) ? Wq : (which == 1 ? Wk : Wv);
  unsigned short* O = (which == 0) ? qb : (which == 1 ? kb : vb);
  int m0 = blockIdx.y * 128, n0 = blockIdx.x * 128;
  __shared__ unsigned short lsA[128 * 64];   // rows 128B, XOR-swizzled
  __shared__ unsigned short lsB[128 * 64];
  int tid = threadIdx.x, l = tid & 63, w = tid >> 6;
  int wm = (w >> 1) * 64, wn = (w & 1) * 64;
  f32x4 acc[4][4] = {};
  for (int kt = 0; kt < K; kt += 64) {
    __syncthreads();
#pragma unroll
    for (int i = 0; i < 4; i++) {                    // stage 128x64 A and B tiles
      int u = i * 256 + tid;
      int row = u >> 3, c16 = u & 7;
      int sw = ((c16 * 16) ^ ((row & 7) << 4));
      u16x8 av = *(const u16x8*)(A + (size_t)(m0 + row) * K + kt + c16 * 8);
      *(u16x8*)((char*)lsA + row * 128 + sw) = av;
      u16x8 bv = *(const u16x8*)(W + (size_t)(n0 + row) * K + kt + c16 * 8);
      *(u16x8*)((char*)lsB + row * 128 + sw) = bv;
    }
    __syncthreads();
#pragma unroll
    for (int kk = 0; kk < 2; kk++) {
      bf16x8 af[4], bfr[4];
      int koff = kk * 64 + (l >> 4) * 16;
#pragma unroll
      for (int mf = 0; mf < 4; mf++) {
        int row = wm + mf * 16 + (l & 15);
        af[mf] = *(const bf16x8*)((char*)lsA + row * 128 + (koff ^ ((row & 7) << 4)));
      }
#pragma unroll
      for (int nf = 0; nf < 4; nf++) {
        int row = wn + nf * 16 + (l & 15);
        bfr[nf] = *(const bf16x8*)((char*)lsB + row * 128 + (koff ^ ((row & 7) << 4)));
      }
#pragma unroll
      for (int mf = 0; mf < 4; mf++)
#pragma unroll
        for (int nf = 0; nf < 4; nf++)
          acc[mf][nf] = __builtin_amdgcn_mfma_f32_16x16x32_bf16(af[mf], bfr[nf], acc[mf][nf], 0, 0, 0);
    }
  }
  // epilogue: C/D layout col=lane&15, row=(lane>>4)*4+reg (m89-verified)
#pragma unroll
  for (int mf = 0; mf < 4; mf++)
#pragma unroll
    for (int nf = 0; nf < 4; nf++)
#pragma unroll
      for (int r = 0; r < 4; r++) {
        int gm = m0 + wm + mf * 16 + (l >> 4) * 4 + r;
        int gn = n0 + wn + nf * 16 + (l & 15);
        int b = gm >> 10, s = gm & 1023;
        int h = gn >> 7,  c = gn & 127;
        O[((size_t)((b * H_ + h) * S_ + s)) * C2_ + c] = f2bf(acc[mf][nf][r]);
      }
}

// ---------------- output GEMM: out = A(4096,2048) @ Wo(1024,2048)^T + resid ----------------
__global__ __launch_bounds__(256) void gemm_out_k(
    const unsigned short* __restrict__ A, const unsigned short* __restrict__ W,
    const float* __restrict__ resid, float* __restrict__ out) {
  const int K = E_;
  int m0 = blockIdx.y * 128, n0 = blockIdx.x * 128;
  __shared__ unsigned short lsA[128 * 64];
  __shared__ unsigned short lsB[128 * 64];
  int tid = threadIdx.x, l = tid & 63, w = tid >> 6;
  int wm = (w >> 1) * 64, wn = (w & 1) * 64;
  f32x4 acc[4][4] = {};
  for (int kt = 0; kt < K; kt += 64) {
    __syncthreads();
#pragma unroll
    for (int i = 0; i < 4; i++) {
      int u = i * 256 + tid;
      int row = u >> 3, c16 = u & 7;
      int sw = ((c16 * 16) ^ ((row & 7) << 4));
      u16x8 av = *(const u16x8*)(A + (size_t)(m0 + row) * K + kt + c16 * 8);
      *(u16x8*)((char*)lsA + row * 128 + sw) = av;
      u16x8 bv = *(const u16x8*)(W + (size_t)(n0 + row) * K + kt + c16 * 8);
      *(u16x8*)((char*)lsB + row * 128 + sw) = bv;
    }
    __syncthreads();
#pragma unroll
    for (int kk = 0; kk < 2; kk++) {
      bf16x8 af[4], bfr[4];
      int koff = kk * 64 + (l >> 4) * 16;
#pragma unroll
      for (int mf = 0; mf < 4; mf++) {
        int row = wm + mf * 16 + (l & 15);
        af[mf] = *(const bf16x8*)((char*)lsA + row * 128 + (koff ^ ((row & 7) << 4)));
      }
#pragma unroll
      for (int nf = 0; nf < 4; nf++) {
        int row = wn + nf * 16 + (l & 15);
        bfr[nf] = *(const bf16x8*)((char*)lsB + row * 128 + (koff ^ ((row & 7) << 4)));
      }
#pragma unroll
      for (int mf = 0; mf < 4; mf++)
#pragma unroll
        for (int nf = 0; nf < 4; nf++)
          acc[mf][nf] = __builtin_amdgcn_mfma_f32_16x16x32_bf16(af[mf], bfr[nf], acc[mf][nf], 0, 0, 0);
    }
  }
#pragma unroll
  for (int mf = 0; mf < 4; mf++)
#pragma unroll
    for (int nf = 0; nf < 4; nf++)
#pragma unroll
      for (int r = 0; r < 4; r++) {
        int gm = m0 + wm + mf * 16 + (l >> 4) * 4 + r;
        int gn = n0 + wn + nf * 16 + (l & 15);
        size_t idx = (size_t)gm * D_ + gn;
        out[idx] = acc[mf][nf][r] + resid[idx];
      }
}

// ---------------- differential flash attention + head LN ----------------
// block = (qt, bh): 64 Q-rows of head bh; 4 waves x 16 rows; KV tiles of 64.
__global__ __launch_bounds__(256) void attn_k(
    const unsigned short* __restrict__ q, const unsigned short* __restrict__ k,
    const unsigned short* __restrict__ v,
    const float* __restrict__ lq1, const float* __restrict__ lk1,
    const float* __restrict__ lq2, const float* __restrict__ lk2,
    const float* __restrict__ hng, const float* __restrict__ hnb,
    const float* __restrict__ lambda_init, const int* __restrict__ dis2,
    unsigned short* __restrict__ out) {
  int qt = blockIdx.x;   // 0..15
  int bh = blockIdx.y;   // 0..63
  int tid = threadIdx.x, l = tid & 63, w = tid >> 6;
  __shared__ unsigned short lsK[64 * 128];    // [key][feat] 256B rows, swizzled
  __shared__ unsigned short lsVt[128 * 64];   // [feat][key] 128B rows, swizzled
  __shared__ unsigned short lsP[4 * 16 * 64]; // per-wave P tile, swizzled
  __shared__ float s_lam, s_osc;

  if (tid < 64) {                             // lambda scalar (wave 0)
    float a = lq1[l] * lk1[l];
    float c = lq2[l] * lk2[l];
#pragma unroll
    for (int m = 32; m; m >>= 1) { a += __shfl_xor(a, m, 64); c += __shfl_xor(c, m, 64); }
    if (l == 0) {
      float li = lambda_init[0];
      float lam = __expf(a) - __expf(c) + li;
      if (dis2[0] != 0) lam = 0.f;
      s_lam = lam;
      s_osc = 1.f - li;
    }
  }

  // Q fragments held in registers (A-frag: row=lane&15, k=(lane>>4)*8+j)
  int qrow = qt * 64 + w * 16 + (l & 15);
  const unsigned short* qrp = q + ((size_t)bh * S_ + qrow) * C2_;
  bf16x8 qf[2][2];
#pragma unroll
  for (int t = 0; t < 2; t++)
#pragma unroll
    for (int kk = 0; kk < 2; kk++)
      qf[t][kk] = *(const bf16x8*)(qrp + t * 64 + kk * 32 + (l >> 4) * 8);

  float mrun[2][4], lrun[2][4];
  f32x4 o[2][8] = {};
#pragma unroll
  for (int t = 0; t < 2; t++)
#pragma unroll
    for (int r = 0; r < 4; r++) { mrun[t][r] = -1e30f; lrun[t][r] = 0.f; }

  const float scale = 0.125f;   // 1/sqrt(64)
  for (int t0 = 0; t0 < S_; t0 += 64) {
    __syncthreads();
    const unsigned short* kbase = k + ((size_t)bh * S_ + t0) * C2_;
#pragma unroll
    for (int i = 0; i < 4; i++) {              // stage K tile (64x128)
      int u = i * 256 + tid, row = u >> 4, c16 = u & 15;
      u16x8 kv8 = *(const u16x8*)(kbase + row * C2_ + c16 * 8);
      *(u16x8*)((char*)lsK + row * 256 + ((c16 * 16) ^ ((row & 7) << 4))) = kv8;
    }
    const unsigned short* vbase = v + ((size_t)bh * S_ + t0) * C2_;
#pragma unroll
    for (int i = 0; i < 4; i++) {              // stage V transposed (lane = key)
      int c = i * 4 + w;
      u16x8 v8 = *(const u16x8*)(vbase + l * C2_ + c * 8);
#pragma unroll
      for (int j = 0; j < 8; j++) {
        int n = c * 8 + j;
        lsVt[n * 64 + (l ^ ((n & 7) << 3))] = v8[j];
      }
    }
    __syncthreads();

#pragma unroll
    for (int t = 0; t < 2; t++) {              // term 1 / term 2
      f32x4 sf[4] = {};
#pragma unroll
      for (int kk = 0; kk < 2; kk++) {
        int koff = t * 128 + kk * 64 + (l >> 4) * 16;
#pragma unroll
        for (int nf = 0; nf < 4; nf++) {
          int row = nf * 16 + (l & 15);
          bf16x8 kf = *(const bf16x8*)((char*)lsK + row * 256 + (koff ^ ((row & 7) << 4)));
          sf[nf] = __builtin_amdgcn_mfma_f32_16x16x32_bf16(qf[t][kk], kf, sf[nf], 0, 0, 0);
        }
      }
      // online softmax (row r lives in the 16-lane group lane>>4)
#pragma unroll
      for (int r = 0; r < 4; r++) {
        float x = fmaxf(fmaxf(sf[0][r], sf[1][r]), fmaxf(sf[2][r], sf[3][r])) * scale;
#pragma unroll
        for (int m = 8; m; m >>= 1) x = fmaxf(x, __shfl_xor(x, m, 64));
        float mn = fmaxf(mrun[t][r], x);
        float alpha = __expf(mrun[t][r] - mn);
        mrun[t][r] = mn;
        float rs = 0.f;
#pragma unroll
        for (int nf = 0; nf < 4; nf++) {
          float p = __expf(sf[nf][r] * scale - mn);
          sf[nf][r] = p;
          rs += p;
        }
#pragma unroll
        for (int m = 8; m; m >>= 1) rs += __shfl_xor(rs, m, 64);
        lrun[t][r] = lrun[t][r] * alpha + rs;
#pragma unroll
        for (int nf2 = 0; nf2 < 8; nf2++) o[t][nf2][r] *= alpha;
      }
      // P: C-layout -> LDS (bf16, swizzled) -> A-layout read
#pragma unroll
      for (int nf = 0; nf < 4; nf++)
#pragma unroll
        for (int r = 0; r < 4; r++) {
          int prow = (l >> 4) * 4 + r;
          int pcol = nf * 16 + (l & 15);
          lsP[w * 1024 + prow * 64 + (pcol ^ ((prow & 7) << 3))] = f2bf(sf[nf][r]);
        }
#pragma unroll
      for (int kk = 0; kk < 2; kk++) {         // PV
        int prow = l & 15;
        bf16x8 pa = *(const bf16x8*)((char*)lsP + w * 2048 + prow * 128 +
                                     ((kk * 64 + (l >> 4) * 16) ^ ((prow & 7) << 4)));
#pragma unroll
        for (int nf2 = 0; nf2 < 8; nf2++) {
          int vrow = nf2 * 16 + (l & 15);
          bf16x8 vf = *(const bf16x8*)((char*)lsVt + vrow * 128 +
                                       ((kk * 64 + (l >> 4) * 16) ^ ((vrow & 7) << 4)));
          o[t][nf2] = __builtin_amdgcn_mfma_f32_16x16x32_bf16(pa, vf, o[t][nf2], 0, 0, 0);
        }
      }
    }
  }

  // epilogue: combine, head-LN over 128, scale, store bf16 (B,S,2048)
  float lam = s_lam, osc = s_osc;
  int b = bh >> 4, h = bh & 15;
#pragma unroll
  for (int r = 0; r < 4; r++) {
    float inv1 = 1.f / lrun[0][r];
    float inv2 = 1.f / lrun[1][r];
    float vals[8];
    float sum = 0.f, sq = 0.f;
#pragma unroll
    for (int nf2 = 0; nf2 < 8; nf2++) {
      float vv = o[0][nf2][r] * inv1 - lam * o[1][nf2][r] * inv2;
      vals[nf2] = vv;
      sum += vv; sq += vv * vv;
    }
#pragma unroll
    for (int m = 8; m; m >>= 1) { sum += __shfl_xor(sum, m, 64); sq += __shfl_xor(sq, m, 64); }
    float mean = sum * (1.f / 128.f);
    float var  = sq * (1.f / 128.f) - mean * mean;
    float rstd = rsqrtf(var + 1e-5f);
    int srow = qt * 64 + w * 16 + (l >> 4) * 4 + r;
    unsigned short* orow = out + ((size_t)(b * S_ + srow)) * E_ + h * C2_;
#pragma unroll
    for (int nf2 = 0; nf2 < 8; nf2++) {
      int feat = nf2 * 16 + (l & 15);
      float y = (vals[nf2] - mean) * rstd * hng[feat] + hnb[feat];
      orow[feat] = f2bf(y * osc);
    }
  }
}

// ---------------- host launcher ----------------
extern "C" void kernel_launch(void* const* d_in, const int* in_sizes, int n_in,
                              void* d_out, int out_size, void* d_ws, size_t ws_size,
                              hipStream_t stream) {
  const float* qtok = (const float*)d_in[0];
  const float* kvtok = (const float*)d_in[1];
  const float* lnqg = (const float*)d_in[2];
  const float* lnqb = (const float*)d_in[3];
  const float* lnkg = (const float*)d_in[4];
  const float* lnkb = (const float*)d_in[5];
  const float* Wq = (const float*)d_in[6];
  const float* Wk = (const float*)d_in[7];
  const float* Wv = (const float*)d_in[8];
  const float* Wo = (const float*)d_in[9];
  const float* lq1 = (const float*)d_in[10];
  const float* lk1 = (const float*)d_in[11];
  const float* lq2 = (const float*)d_in[12];
  const float* lk2 = (const float*)d_in[13];
  const float* hng = (const float*)d_in[14];
  const float* hnb = (const float*)d_in[15];
  const float* lami = (const float*)d_in[16];
  const int*   dis2 = (const int*)d_in[17];
  float* outp = (float*)d_out;

  char* ws = (char*)d_ws;
  const size_t MB = 1024 * 1024;
  // layout (80 MB peak): [0,16) qln+kvln, later reused as attn_out; [16,32) bf16 weights;
  // [32,80) q/k/v in (b,h,s,c) layout.
  unsigned short* qln    = (unsigned short*)(ws + 0);
  unsigned short* kvln   = (unsigned short*)(ws + 8 * MB);
  unsigned short* attn_o = (unsigned short*)(ws + 0);        // aliases qln/kvln (dead by then)
  unsigned short* Wqb = (unsigned short*)(ws + 16 * MB);
  unsigned short* Wkb = (unsigned short*)(ws + 20 * MB);
  unsigned short* Wvb = (unsigned short*)(ws + 24 * MB);
  unsigned short* Wob = (unsigned short*)(ws + 28 * MB);
  unsigned short* qb  = (unsigned short*)(ws + 32 * MB);
  unsigned short* kb  = (unsigned short*)(ws + 48 * MB);
  unsigned short* vb  = (unsigned short*)(ws + 64 * MB);

  ln_cast_k<<<dim3(4096), dim3(256), 0, stream>>>(qtok, lnqg, lnqb, qln);
  ln_cast_k<<<dim3(4096), dim3(256), 0, stream>>>(kvtok, lnkg, lnkb, kvln);
  cast_k<<<dim3(2048), dim3(256), 0, stream>>>(Wq, Wqb, 512 * 1024);
  cast_k<<<dim3(2048), dim3(256), 0, stream>>>(Wk, Wkb, 512 * 1024);
  cast_k<<<dim3(2048), dim3(256), 0, stream>>>(Wv, Wvb, 512 * 1024);
  cast_k<<<dim3(2048), dim3(256), 0, stream>>>(Wo, Wob, 512 * 1024);
  gemm_proj_k<<<dim3(16, 32, 3), dim3(256), 0, stream>>>(qln, kvln, Wqb, Wkb, Wvb, qb, kb, vb);
  attn_k<<<dim3(16, 64), dim3(256), 0, stream>>>(qb, kb, vb, lq1, lk1, lq2, lk2,
                                                 hng, hnb, lami, dis2, attn_o);
  gemm_out_k<<<dim3(8, 32), dim3(256), 0, stream>>>(attn_o, Wob, qtok, outp);
}